// Round 5
// baseline (319.901 us; speedup 1.0000x reference)
//
#include <hip/hip_runtime.h>
#include <hip/hip_cooperative_groups.h>
#include <math.h>

namespace cg = cooperative_groups;

#define IMG_H 4096
#define IMG_W 4096
#define TS 64
#define HALO 3
#define TW 70              // TS + 2*HALO
#define THS 71             // th LDS row stride (odd -> conflict-free)
#define HMS 65             // hm LDS row stride (odd)
#define NBINS 4096         // fallback: linear value bins over [-4, 4]
#define GRIDB 512          // fused grid: 2 blocks/CU on 256 CUs (co-resident)
#define NTHR 512
#define CAPB 4096          // per-block candidate region cap (expected ~52)
// speculative window: sample median of 16.7M N(0,1) is 0 +- 3.1e-4 (1 sigma);
// [-1/512, +1/512) covers +-6.3 sigma. Exact fallback path guards it.
#define WLO (-0.001953125f)
#define WHI ( 0.001953125f)
#define MCAP 1024          // selected-sub-bin member cap (else exact fallback)
#define NSUB 2048          // linear sub-bins across the window

// legacy 3-dispatch path constants
#define CBLK 1024

struct SelState { float median; };

__device__ __forceinline__ unsigned f2u(float f) {
    unsigned b = __float_as_uint(f);
    unsigned mask = (unsigned)(-(int)(b >> 31)) | 0x80000000u;
    return b ^ mask;
}
__device__ __forceinline__ float u2f(unsigned u) {
    unsigned mask = (u >> 31) ? 0x80000000u : 0xFFFFFFFFu;
    return __uint_as_float(u ^ mask);
}
__device__ __forceinline__ int val_bin(float v) {
    float t = (v + 4.0f) * 512.0f;
    int b = (int)t;
    b = b < 0 ? 0 : b;
    b = b > (NBINS - 1) ? (NBINS - 1) : b;
    return b;
}
__device__ __forceinline__ int sub_bin(float v) {
    float t = (v - WLO) * (float)(NSUB * 256);
    int b = (int)t;
    b = b < 0 ? 0 : b;
    b = b > (NSUB - 1) ? (NSUB - 1) : b;
    return b;
}

// ---------------------------------------------------------------------------
// FUSED single cooperative kernel: count/compact -> median select -> nms.
// 3 grid syncs replace 2 dispatch boundaries + 2 launch overheads.
// ---------------------------------------------------------------------------
union SMem {
    struct { unsigned buf[CAPB]; unsigned wred[8]; unsigned lcnt; } a; // 16.4KB
    struct { unsigned lh[NBINS];                                      // 16.4KB
             unsigned s_below, s_M, s_ovf, s_sb, s_kr2, s_cnt;
             unsigned s_bin, s_krem, s_m, s_pref, s_kr;
             float s_med; } b;
    struct { float th[TW * THS]; float hm[TW * HMS]; } c;             // 38.0KB
};

__global__ __launch_bounds__(NTHR, 4) void fused_nms(
    const float4* __restrict__ x4, int n4, unsigned K,
    const float* __restrict__ x, float* __restrict__ out,
    unsigned* __restrict__ candB,      // fallback scratch (= d_out)
    SelState* __restrict__ st,
    unsigned* __restrict__ belowCnt,   // [GRIDB]
    unsigned* __restrict__ candCnt,    // [GRIDB]
    unsigned* __restrict__ candA,      // [GRIDB*CAPB]
    unsigned* __restrict__ ghist,      // [NSUB]
    unsigned* __restrict__ gmem,       // [MCAP]
    unsigned* __restrict__ gmcnt, unsigned* __restrict__ gfb)
{
    __shared__ SMem sm;
    cg::grid_group grid = cg::this_grid();
    const int t = threadIdx.x;
    const int b = blockIdx.x;
    const unsigned lane = t & 63, wid = t >> 6;

    // ------------------- phase A: count + per-block compact ----------------
    if (t == 0) sm.a.lcnt = 0;
    __syncthreads();
    if (b == 0) {                       // zero phase-B global state
        for (int i = t; i < NSUB; i += NTHR) ghist[i] = 0;
        if (t == 0) { *gmcnt = 0; *gfb = 0; }
    }
    unsigned below = 0;
    const int gid = b * NTHR + t;
    const int stride = GRIDB * NTHR;    // 262144
    if (n4 == 16 * stride) {
        #pragma unroll
        for (int half = 0; half < 2; half++) {
            float4 v[8];
            #pragma unroll
            for (int j = 0; j < 8; j++) v[j] = x4[gid + (half * 8 + j) * stride];
            #pragma unroll
            for (int j = 0; j < 8; j++) {
                float vs[4] = {v[j].x, v[j].y, v[j].z, v[j].w};
                #pragma unroll
                for (int u = 0; u < 4; u++) {
                    float vv = vs[u];
                    below += (vv < WLO) ? 1u : 0u;
                    if (vv >= WLO && vv < WHI) {
                        unsigned p = atomicAdd(&sm.a.lcnt, 1u);
                        if (p < CAPB) sm.a.buf[p] = f2u(vv);
                    }
                }
            }
        }
    } else {
        for (int i = gid; i < n4; i += stride) {
            float4 v = x4[i];
            float vs[4] = {v.x, v.y, v.z, v.w};
            #pragma unroll
            for (int u = 0; u < 4; u++) {
                float vv = vs[u];
                below += (vv < WLO) ? 1u : 0u;
                if (vv >= WLO && vv < WHI) {
                    unsigned p = atomicAdd(&sm.a.lcnt, 1u);
                    if (p < CAPB) sm.a.buf[p] = f2u(vv);
                }
            }
        }
    }
    #pragma unroll
    for (int off = 32; off >= 1; off >>= 1) below += __shfl_down(below, off, 64);
    if (lane == 0) sm.a.wred[wid] = below;
    __syncthreads();
    if (t == 0) {
        unsigned tot = 0;
        #pragma unroll
        for (int w = 0; w < 8; w++) tot += sm.a.wred[w];
        belowCnt[b] = tot;
        candCnt[b] = sm.a.lcnt;         // raw; > CAPB signals overflow
    }
    unsigned m0 = sm.a.lcnt; if (m0 > CAPB) m0 = CAPB;
    for (unsigned i = t; i < m0; i += NTHR) candA[(unsigned)b * CAPB + i] = sm.a.buf[i];
    grid.sync();                        // ---- sync 1 ----

    // ------------------- B1: redundant totals + global sub-bin hist --------
    {
        const unsigned ccv = candCnt[t];        // GRIDB == NTHR: 1 entry/thread
        unsigned bsum = belowCnt[t];
        unsigned csum = ccv;
        unsigned osum = (ccv > CAPB) ? 1u : 0u;
        #pragma unroll
        for (int off = 32; off >= 1; off >>= 1) {
            bsum += __shfl_down(bsum, off, 64);
            csum += __shfl_down(csum, off, 64);
            osum += __shfl_down(osum, off, 64);
        }
        if (lane == 0) { sm.b.lh[wid] = bsum; sm.b.lh[8 + wid] = csum; sm.b.lh[16 + wid] = osum; }
        __syncthreads();
        if (t == 0) {
            unsigned bb = 0, cc = 0, oo = 0;
            #pragma unroll
            for (int w = 0; w < 8; w++) { bb += sm.b.lh[w]; cc += sm.b.lh[8 + w]; oo += sm.b.lh[16 + w]; }
            sm.b.s_below = bb; sm.b.s_M = cc; sm.b.s_ovf = oo;
        }
        __syncthreads();
    }
    {   // each block adds its own region to the global sub-bin histogram
        unsigned cc = candCnt[b]; if (cc > CAPB) cc = CAPB;
        for (unsigned j = t; j < cc; j += NTHR)
            atomicAdd(&ghist[sub_bin(u2f(candA[(unsigned)b * CAPB + j]))], 1u);
    }
    grid.sync();                        // ---- sync 2 ----

    // ------------------- B2: redundant scan -> gather (or exact fallback) --
    const unsigned belowT = sm.b.s_below, Mtot = sm.b.s_M;
    const bool fastok = (sm.b.s_ovf == 0u) && (K >= belowT) && (K - belowT < Mtot);
    if (fastok) {
        const unsigned kRem = K - belowT;
        unsigned d[4], local = 0;
        #pragma unroll
        for (int j = 0; j < 4; j++) { d[j] = ghist[t * 4 + j]; local += d[j]; }
        unsigned s = local;
        #pragma unroll
        for (int off = 1; off < 64; off <<= 1) {
            unsigned u = __shfl_up(s, off, 64);
            if (lane >= off) s += u;
        }
        if (lane == 63) sm.b.lh[wid] = s;
        __syncthreads();
        unsigned base = 0;
        for (unsigned w = 0; w < wid; w++) base += sm.b.lh[w];
        unsigned excl = base + s - local;
        if (kRem >= excl && kRem < excl + local) {
            unsigned cum = excl;
            #pragma unroll
            for (int j = 0; j < 4; j++) {
                if (kRem < cum + d[j]) {
                    sm.b.s_sb = (unsigned)(t * 4 + j);
                    sm.b.s_kr2 = kRem - cum;
                    sm.b.s_cnt = d[j];
                    break;
                }
                cum += d[j];
            }
        }
        __syncthreads();
    }
    bool needfb = true;
    if (fastok) needfb = (sm.b.s_cnt > MCAP);
    if (!needfb) {
        unsigned cc = candCnt[b]; if (cc > CAPB) cc = CAPB;
        const unsigned sb = sm.b.s_sb;
        for (unsigned j = t; j < cc; j += NTHR) {
            unsigned key = candA[(unsigned)b * CAPB + j];
            if ((unsigned)sub_bin(u2f(key)) == sb) {
                unsigned p = atomicAdd(gmcnt, 1u);
                if (p < MCAP) gmem[p] = key;
            }
        }
    } else if (b == 0) {
        // ---- exact fallback (cold, any distribution): block 0, ~ms ----
        for (int i = t; i < NBINS; i += NTHR) sm.b.lh[i] = 0;
        __syncthreads();
        for (int i = t; i < n4; i += NTHR) {
            float4 v = x4[i];
            atomicAdd(&sm.b.lh[val_bin(v.x)], 1u);
            atomicAdd(&sm.b.lh[val_bin(v.y)], 1u);
            atomicAdd(&sm.b.lh[val_bin(v.z)], 1u);
            atomicAdd(&sm.b.lh[val_bin(v.w)], 1u);
        }
        __syncthreads();
        if (t == 0) {
            unsigned cum = 0;
            for (int i = 0; i < NBINS; i++) {
                unsigned c = sm.b.lh[i];
                if (K < cum + c) { sm.b.s_bin = (unsigned)i; sm.b.s_krem = K - cum; break; }
                cum += c;
            }
            sm.b.s_m = 0;
        }
        __syncthreads();
        {
            const unsigned bin = sm.b.s_bin;
            for (int i = t; i < n4; i += NTHR) {
                float4 v = x4[i];
                float vs[4] = {v.x, v.y, v.z, v.w};
                #pragma unroll
                for (int j = 0; j < 4; j++) {
                    if ((unsigned)val_bin(vs[j]) == bin) {
                        unsigned p = atomicAdd(&sm.b.s_m, 1u);
                        candB[p] = f2u(vs[j]);
                    }
                }
            }
            __syncthreads();
        }
        const int M2 = (int)sm.b.s_m;
        if (t == 0) { sm.b.s_pref = 0; sm.b.s_kr = sm.b.s_krem; }
        __syncthreads();
        for (int p = 0; p < 3; p++) {
            const int shift = (p == 0) ? 21 : ((p == 1) ? 10 : 0);
            const int bits  = (p == 2) ? 10 : 11;
            const int nb    = 1 << bits;
            for (int i = t; i < nb; i += NTHR) sm.b.lh[i] = 0;
            __syncthreads();
            const unsigned pref = sm.b.s_pref;
            for (int i = t; i < M2; i += NTHR) {
                unsigned u = candB[i];
                bool ok = (p == 0) || ((u >> ((p == 1) ? 21 : 10)) == pref);
                if (ok) atomicAdd(&sm.b.lh[(u >> shift) & (unsigned)(nb - 1)], 1u);
            }
            __syncthreads();
            if (t == 0) {
                unsigned kr = sm.b.s_kr, cum = 0;
                for (int i = 0; i < nb; i++) {
                    unsigned c = sm.b.lh[i];
                    if (kr < cum + c) { sm.b.s_pref = (pref << bits) | (unsigned)i; sm.b.s_kr = kr - cum; break; }
                    cum += c;
                }
            }
            __syncthreads();
        }
        if (t == 0) { st->median = u2f(sm.b.s_pref); *gfb = 1u; }
    }
    grid.sync();                        // ---- sync 3 ----

    // ------------------- B3: redundant O(m^2) select -----------------------
    float med;
    if (*gfb) {
        med = st->median;
    } else {
        const unsigned m = *gmcnt;      // == s_cnt <= MCAP, >= 1
        const unsigned kr2 = sm.b.s_kr2;
        for (unsigned tt = t; tt < m; tt += NTHR) {
            unsigned ku = gmem[tt], c = 0, e = 0;
            for (unsigned j = 0; j < m; j++) {
                unsigned kj = gmem[j];
                c += (kj < ku);
                e += (kj == ku);
            }
            if (c <= kr2 && kr2 < c + e) sm.b.s_med = u2f(ku);
        }
        __syncthreads();
        med = sm.b.s_med;
    }

    // ------------------- phase C: 8 nms tiles per block --------------------
    const float NEGINF = -__builtin_inff();
    for (int it = 0; it < 8; ++it) {
        __syncthreads();                // protect LDS reuse across tiles/phases
        const int tile = b * 8 + it;    // 512*8 == 4096 tiles
        const int bx = tile & 63, by = tile >> 6;
        const int gy0 = by * TS - HALO;
        const int gcol0 = bx * TS - 4;  // float4-aligned staging start

        if (bx >= 1 && bx <= 62 && by >= 1 && by <= 62) {
            #pragma unroll
            for (int k = 0; k < 3; k++) {
                int task = t + k * NTHR;
                if (task < TW * 18) {
                    int r = task / 18, q = task - r * 18;
                    const float4 v = *(const float4*)&x[(gy0 + r) * IMG_W + (gcol0 + q * 4)];
                    float vs[4] = {v.x, v.y, v.z, v.w};
                    #pragma unroll
                    for (int cmp = 0; cmp < 4; cmp++) {
                        int c = q * 4 - 1 + cmp;
                        if ((unsigned)c < (unsigned)TW)
                            sm.c.th[r * THS + c] = (vs[cmp] < med) ? 0.0f : vs[cmp];
                    }
                }
            }
        } else {
            for (int task = t; task < TW * 18; task += NTHR) {
                int r = task / 18, q = task - r * 18;
                int gy = gy0 + r;
                int gxb = gcol0 + q * 4;
                bool rowok = (gy >= 0 && gy < IMG_H);
                float vs[4];
                if (rowok && gxb >= 0 && gxb + 4 <= IMG_W) {
                    float4 v = *(const float4*)&x[gy * IMG_W + gxb];
                    vs[0] = v.x; vs[1] = v.y; vs[2] = v.z; vs[3] = v.w;
                } else if (rowok) {
                    #pragma unroll
                    for (int cmp = 0; cmp < 4; cmp++) {
                        int gx = gxb + cmp;
                        vs[cmp] = (gx >= 0 && gx < IMG_W) ? x[gy * IMG_W + gx] : NEGINF;
                    }
                } else {
                    vs[0] = vs[1] = vs[2] = vs[3] = NEGINF;
                }
                #pragma unroll
                for (int cmp = 0; cmp < 4; cmp++) {
                    int c = q * 4 - 1 + cmp;
                    if ((unsigned)c < (unsigned)TW) {
                        float v = vs[cmp];
                        v = (v == NEGINF) ? v : ((v < med) ? 0.0f : v);
                        sm.c.th[r * THS + c] = v;
                    }
                }
            }
        }
        __syncthreads();

        // horizontal 7-max
        for (int task = t; task < TW * 8; task += NTHR) {
            int r = task % TW;
            int c0 = (task / TW) * 8;
            float w[7];
            #pragma unroll
            for (int i = 0; i < 14; i++) {
                w[i % 7] = sm.c.th[r * THS + c0 + i];
                if (i >= 6) {
                    float m = w[0];
                    #pragma unroll
                    for (int k = 1; k < 7; k++) m = fmaxf(m, w[k]);
                    sm.c.hm[r * HMS + c0 + i - 6] = m;
                }
            }
        }
        __syncthreads();

        // vertical 7-max + binarize*x
        {
            const int c = t & 63;
            const int rr0 = (t >> 6) * 8;
            float w[7];
            #pragma unroll
            for (int i = 0; i < 14; i++) {
                w[i % 7] = sm.c.hm[(rr0 + i) * HMS + c];
                if (i >= 6) {
                    int R = rr0 + i - 6;
                    float m = w[0];
                    #pragma unroll
                    for (int k = 1; k < 7; k++) m = fmaxf(m, w[k]);
                    float tv = sm.c.th[(R + HALO) * THS + (c + HALO)];
                    int gy = by * TS + R;
                    int gx = bx * TS + c;
                    float o = 0.0f;
                    if (tv == m) {
                        o = (tv != 0.0f) ? tv : x[gy * IMG_W + gx];
                    }
                    out[gy * IMG_W + gx] = o;
                }
            }
        }
    }
}

// ---------------------------------------------------------------------------
// Legacy 3-dispatch path (fallback if cooperative launch is rejected).
// Identical to the round-4 verified kernels.
// ---------------------------------------------------------------------------
__global__ __launch_bounds__(512, 8) void count_compact(
    const float4* __restrict__ x4, int n4,
    unsigned* __restrict__ belowCnt, unsigned* __restrict__ candCnt,
    unsigned* __restrict__ candA)
{
    __shared__ unsigned buf[CAPB];
    __shared__ unsigned wred[8];
    __shared__ unsigned lcnt;
    const int t = threadIdx.x;
    if (t == 0) lcnt = 0;
    __syncthreads();
    unsigned below = 0;
    const int idx = blockIdx.x * 512 + t;
    const int stride = CBLK * 512;
    for (int i = idx; i < n4; i += stride) {
        float4 v = x4[i];
        float vs[4] = {v.x, v.y, v.z, v.w};
        #pragma unroll
        for (int u = 0; u < 4; u++) {
            float vv = vs[u];
            below += (vv < WLO) ? 1u : 0u;
            if (vv >= WLO && vv < WHI) {
                unsigned p = atomicAdd(&lcnt, 1u);
                if (p < CAPB) buf[p] = f2u(vv);
            }
        }
    }
    #pragma unroll
    for (int off = 32; off >= 1; off >>= 1) below += __shfl_down(below, off, 64);
    if ((t & 63) == 0) wred[t >> 6] = below;
    __syncthreads();
    if (t == 0) {
        unsigned tot = 0;
        #pragma unroll
        for (int w = 0; w < 8; w++) tot += wred[w];
        belowCnt[blockIdx.x] = tot;
        candCnt[blockIdx.x] = lcnt;
    }
    unsigned m = lcnt; if (m > CAPB) m = CAPB;
    const unsigned gbase = (unsigned)blockIdx.x * CAPB;
    for (unsigned i = t; i < m; i += 512) candA[gbase + i] = buf[i];
}

__global__ __launch_bounds__(1024) void finalize_fb(
    const float4* __restrict__ x4, int n4, unsigned K,
    const unsigned* __restrict__ belowCnt, const unsigned* __restrict__ candCnt,
    const unsigned* __restrict__ candA, unsigned* __restrict__ candB,
    SelState* __restrict__ st)
{
    __shared__ unsigned hist[NSUB];
    __shared__ unsigned mem[MCAP];
    __shared__ unsigned lh[NBINS];
    __shared__ unsigned ccs[CBLK];
    __shared__ unsigned wsA[16], wsB[16], wsC[16];
    __shared__ unsigned s_below, s_M, s_ovf, s_sb, s_kr2, mcnt;
    __shared__ unsigned s_bin, s_krem, s_m, s_pref, s_kr;
    const int t = threadIdx.x;
    const unsigned lane = t & 63, wid = t >> 6;
    const unsigned rbase = wid * 64u;
    unsigned key[64];
    #pragma unroll
    for (int g = 0; g < 64; g++)
        key[g] = candA[(rbase + (unsigned)g) * CAPB + lane];
    {
        const unsigned cc = candCnt[t];
        ccs[t] = cc;
        unsigned bsum = belowCnt[t];
        unsigned csum = cc;
        unsigned osum = (cc > CAPB) ? 1u : 0u;
        #pragma unroll
        for (int off = 32; off >= 1; off >>= 1) {
            bsum += __shfl_down(bsum, off, 64);
            csum += __shfl_down(csum, off, 64);
            osum += __shfl_down(osum, off, 64);
        }
        if (lane == 0) { wsA[wid] = bsum; wsB[wid] = csum; wsC[wid] = osum; }
        if (t == 0) mcnt = 0;
        for (int i = t; i < NSUB; i += 1024) hist[i] = 0;
        __syncthreads();
        if (t == 0) {
            unsigned bb = 0, cc2 = 0, oo = 0;
            #pragma unroll
            for (int w = 0; w < 16; w++) { bb += wsA[w]; cc2 += wsB[w]; oo += wsC[w]; }
            s_below = bb; s_M = cc2; s_ovf = oo;
        }
        __syncthreads();
    }
    const unsigned below = s_below, M = s_M;
    bool resolved = false;
    if (s_ovf == 0u && K >= below && (K - below) < M) {
        const unsigned kRem = K - below;
        #pragma unroll
        for (int g = 0; g < 64; g++)
            if (lane < ccs[rbase + (unsigned)g])
                atomicAdd(&hist[sub_bin(u2f(key[g]))], 1u);
        for (int r = t; r < CBLK; r += 1024) {
            const unsigned cc = ccs[r];
            for (unsigned j = 64; j < cc; j++)
                atomicAdd(&hist[sub_bin(u2f(candA[(unsigned)r * CAPB + j]))], 1u);
        }
        __syncthreads();
        unsigned d0 = hist[t * 2], d1 = hist[t * 2 + 1];
        unsigned loc2 = d0 + d1;
        unsigned s2 = loc2;
        #pragma unroll
        for (int off = 1; off < 64; off <<= 1) {
            unsigned u = __shfl_up(s2, off, 64);
            if (lane >= off) s2 += u;
        }
        if (lane == 63) wsA[wid] = s2;
        __syncthreads();
        unsigned base2 = 0;
        for (unsigned w = 0; w < wid; w++) base2 += wsA[w];
        unsigned excl2 = base2 + s2 - loc2;
        if (kRem >= excl2 && kRem < excl2 + loc2) {
            if (kRem < excl2 + d0) { s_sb = (unsigned)(t * 2);     s_kr2 = kRem - excl2; }
            else                   { s_sb = (unsigned)(t * 2 + 1); s_kr2 = kRem - excl2 - d0; }
        }
        __syncthreads();
        const int sb = (int)s_sb;
        #pragma unroll
        for (int g = 0; g < 64; g++) {
            if (lane < ccs[rbase + (unsigned)g] && sub_bin(u2f(key[g])) == sb) {
                unsigned p = atomicAdd(&mcnt, 1u);
                if (p < MCAP) mem[p] = key[g];
            }
        }
        for (int r = t; r < CBLK; r += 1024) {
            const unsigned cc = ccs[r];
            for (unsigned j = 64; j < cc; j++) {
                unsigned k2 = candA[(unsigned)r * CAPB + j];
                if (sub_bin(u2f(k2)) == sb) {
                    unsigned p = atomicAdd(&mcnt, 1u);
                    if (p < MCAP) mem[p] = k2;
                }
            }
        }
        __syncthreads();
        if (mcnt <= MCAP) {
            const unsigned m = mcnt, kr2 = s_kr2;
            if ((unsigned)t < m) {
                unsigned ku = mem[t], c = 0, e = 0;
                for (unsigned j = 0; j < m; j++) {
                    unsigned kj = mem[j];
                    c += (kj < ku);
                    e += (kj == ku);
                }
                if (c <= kr2 && kr2 < c + e) st->median = u2f(ku);
            }
            resolved = true;
        }
    }
    if (resolved) return;
    __syncthreads();
    for (int i = t; i < NBINS; i += 1024) lh[i] = 0;
    __syncthreads();
    for (int i = t; i < n4; i += 1024) {
        float4 v = x4[i];
        atomicAdd(&lh[val_bin(v.x)], 1u);
        atomicAdd(&lh[val_bin(v.y)], 1u);
        atomicAdd(&lh[val_bin(v.z)], 1u);
        atomicAdd(&lh[val_bin(v.w)], 1u);
    }
    __syncthreads();
    {
        unsigned cb[4];
        unsigned local = 0;
        #pragma unroll
        for (int j = 0; j < 4; j++) { cb[j] = lh[t * 4 + j]; local += cb[j]; }
        unsigned s = local;
        #pragma unroll
        for (int off = 1; off < 64; off <<= 1) {
            unsigned u = __shfl_up(s, off, 64);
            if (lane >= off) s += u;
        }
        if (lane == 63) wsA[wid] = s;
        __syncthreads();
        unsigned base = 0;
        for (unsigned w = 0; w < wid; w++) base += wsA[w];
        unsigned excl = base + s - local;
        if (K >= excl && K < excl + local) {
            unsigned cum = excl;
            #pragma unroll
            for (int j = 0; j < 4; j++) {
                if (K < cum + cb[j]) { s_bin = (unsigned)(t * 4 + j); s_krem = K - cum; break; }
                cum += cb[j];
            }
        }
        if (t == 0) s_m = 0;
        __syncthreads();
    }
    {
        const int bb = (int)s_bin;
        for (int i = t; i < n4; i += 1024) {
            float4 v = x4[i];
            float vs[4] = {v.x, v.y, v.z, v.w};
            #pragma unroll
            for (int j = 0; j < 4; j++) {
                if (val_bin(vs[j]) == bb) {
                    unsigned p = atomicAdd(&s_m, 1u);
                    candB[p] = f2u(vs[j]);
                }
            }
        }
        __syncthreads();
    }
    const int M2 = (int)s_m;
    if (t == 0) { s_pref = 0; s_kr = s_krem; }
    for (int p = 0; p < 3; p++) {
        const int shift = (p == 0) ? 21 : ((p == 1) ? 10 : 0);
        const int bits  = (p == 2) ? 10 : 11;
        const int nb    = 1 << bits;
        for (int i = t; i < nb; i += 1024) lh[i] = 0;
        __syncthreads();
        const unsigned pref = s_pref;
        for (int i = t; i < M2; i += 1024) {
            unsigned u = candB[i];
            bool ok = (p == 0) || ((u >> ((p == 1) ? 21 : 10)) == pref);
            if (ok) atomicAdd(&lh[(u >> shift) & (unsigned)(nb - 1)], 1u);
        }
        __syncthreads();
        const int P = nb >> 10;
        unsigned c0 = lh[t * (P ? P : 1)];
        unsigned c1 = (P == 2) ? lh[t * 2 + 1] : 0u;
        if (P == 0) { c0 = (t < nb) ? lh[t] : 0u; c1 = 0u; }
        unsigned local = c0 + c1;
        unsigned s = local;
        #pragma unroll
        for (int off = 1; off < 64; off <<= 1) {
            unsigned u = __shfl_up(s, off, 64);
            if (lane >= off) s += u;
        }
        if (lane == 63) wsA[wid] = s;
        __syncthreads();
        unsigned base = 0;
        for (unsigned w = 0; w < wid; w++) base += wsA[w];
        unsigned excl = base + s - local;
        unsigned kRem2 = s_kr;
        __syncthreads();
        if (kRem2 >= excl && kRem2 < excl + local) {
            if (P == 2) {
                if (kRem2 < excl + c0) { s_pref = (pref << bits) | (unsigned)(t * 2);     s_kr = kRem2 - excl; }
                else                   { s_pref = (pref << bits) | (unsigned)(t * 2 + 1); s_kr = kRem2 - excl - c0; }
            } else {
                s_pref = (pref << bits) | (unsigned)t;
                s_kr = kRem2 - excl;
            }
        }
        __syncthreads();
    }
    if (t == 0) st->median = u2f(s_pref);
}

__global__ __launch_bounds__(512) void nms_kernel(
    const float* __restrict__ x, float* __restrict__ out,
    const SelState* __restrict__ st)
{
    __shared__ float th[TW * THS];
    __shared__ float hm[TW * HMS];
    const float med = st->median;
    const float NEGINF = -__builtin_inff();
    const int bx = blockIdx.x, by = blockIdx.y;
    const int gy0 = by * TS - HALO;
    const int gcol0 = bx * TS - 4;
    if (bx >= 1 && bx <= 62 && by >= 1 && by <= 62) {
        #pragma unroll
        for (int k = 0; k < 3; k++) {
            int task = threadIdx.x + k * 512;
            if (task < TW * 18) {
                int r = task / 18, q = task - r * 18;
                const float4 v = *(const float4*)&x[(gy0 + r) * IMG_W + (gcol0 + q * 4)];
                float vs[4] = {v.x, v.y, v.z, v.w};
                #pragma unroll
                for (int cmp = 0; cmp < 4; cmp++) {
                    int c = q * 4 - 1 + cmp;
                    if ((unsigned)c < (unsigned)TW)
                        th[r * THS + c] = (vs[cmp] < med) ? 0.0f : vs[cmp];
                }
            }
        }
    } else {
        for (int task = threadIdx.x; task < TW * 18; task += 512) {
            int r = task / 18, q = task - r * 18;
            int gy = gy0 + r;
            int gxb = gcol0 + q * 4;
            bool rowok = (gy >= 0 && gy < IMG_H);
            float vs[4];
            if (rowok && gxb >= 0 && gxb + 4 <= IMG_W) {
                float4 v = *(const float4*)&x[gy * IMG_W + gxb];
                vs[0] = v.x; vs[1] = v.y; vs[2] = v.z; vs[3] = v.w;
            } else if (rowok) {
                #pragma unroll
                for (int cmp = 0; cmp < 4; cmp++) {
                    int gx = gxb + cmp;
                    vs[cmp] = (gx >= 0 && gx < IMG_W) ? x[gy * IMG_W + gx] : NEGINF;
                }
            } else {
                vs[0] = vs[1] = vs[2] = vs[3] = NEGINF;
            }
            #pragma unroll
            for (int cmp = 0; cmp < 4; cmp++) {
                int c = q * 4 - 1 + cmp;
                if ((unsigned)c < (unsigned)TW) {
                    float v = vs[cmp];
                    v = (v == NEGINF) ? v : ((v < med) ? 0.0f : v);
                    th[r * THS + c] = v;
                }
            }
        }
    }
    __syncthreads();
    for (int task = threadIdx.x; task < TW * 8; task += 512) {
        int r = task % TW;
        int c0 = (task / TW) * 8;
        float w[7];
        #pragma unroll
        for (int i = 0; i < 14; i++) {
            w[i % 7] = th[r * THS + c0 + i];
            if (i >= 6) {
                float m = w[0];
                #pragma unroll
                for (int k = 1; k < 7; k++) m = fmaxf(m, w[k]);
                hm[r * HMS + c0 + i - 6] = m;
            }
        }
    }
    __syncthreads();
    {
        const int c = threadIdx.x & 63;
        const int rr0 = (threadIdx.x >> 6) * 8;
        float w[7];
        #pragma unroll
        for (int i = 0; i < 14; i++) {
            w[i % 7] = hm[(rr0 + i) * HMS + c];
            if (i >= 6) {
                int R = rr0 + i - 6;
                float m = w[0];
                #pragma unroll
                for (int k = 1; k < 7; k++) m = fmaxf(m, w[k]);
                float tv = th[(R + HALO) * THS + (c + HALO)];
                int gy = by * TS + R;
                int gx = bx * TS + c;
                float o = 0.0f;
                if (tv == m) {
                    o = (tv != 0.0f) ? tv : x[gy * IMG_W + gx];
                }
                out[gy * IMG_W + gx] = o;
            }
        }
    }
}

extern "C" void kernel_launch(void* const* d_in, const int* in_sizes, int n_in,
                              void* d_out, int out_size, void* d_ws, size_t ws_size,
                              hipStream_t stream)
{
    const float* x = (const float*)d_in[0];
    float* out = (float*)d_out;
    const int n = in_sizes[0];                  // 16777216
    const unsigned K = (unsigned)((n - 1) / 2); // rank of lower-middle element
    char* ws = (char*)d_ws;

    SelState* st       = (SelState*)ws;
    unsigned* gfb      = (unsigned*)(ws + 64);
    unsigned* gmcnt    = (unsigned*)(ws + 128);
    unsigned* ghist    = (unsigned*)(ws + 256);      // 8 KB
    unsigned* belowCnt = (unsigned*)(ws + 16384);    // [512] (fused) / [1024] (legacy reuse below)
    unsigned* candCnt  = (unsigned*)(ws + 24576);
    unsigned* gmem     = (unsigned*)(ws + 32768);    // 4 KB
    unsigned* candA    = (unsigned*)(ws + ws_size / 2);

    const float4* x4 = (const float4*)x;
    unsigned* candB = (unsigned*)d_out;
    int n4 = n / 4;
    unsigned Kv = K;

    void* args[] = { (void*)&x4, (void*)&n4, (void*)&Kv, (void*)&x, (void*)&out,
                     (void*)&candB, (void*)&st, (void*)&belowCnt, (void*)&candCnt,
                     (void*)&candA, (void*)&ghist, (void*)&gmem, (void*)&gmcnt,
                     (void*)&gfb };
    hipError_t err = hipLaunchCooperativeKernel((void*)fused_nms,
                                                dim3(GRIDB), dim3(NTHR),
                                                args, 0, stream);
    if (err != hipSuccess) {
        // legacy 3-dispatch path (proven): regions sized for CBLK=1024
        count_compact<<<CBLK, 512, 0, stream>>>(x4, n4, belowCnt, candCnt, candA);
        finalize_fb<<<1, 1024, 0, stream>>>(x4, n4, K, belowCnt, candCnt, candA,
                                            candB, st);
        dim3 fg(IMG_W / TS, IMG_H / TS);
        nms_kernel<<<fg, 512, 0, stream>>>(x, out, st);
    }
}